// Round 5
// baseline (53.288 us; speedup 1.0000x reference)
//
#include <hip/hip_runtime.h>

#define N_TOT 8192
#define BSZ   4096
#define DIM   256

typedef __attribute__((ext_vector_type(8))) short bf16x8;
typedef __attribute__((ext_vector_type(4))) float f32x4;

// zb is pre-scaled by sqrt(2*log2(e)) so that acc = 2*log2(e)*sim and
// exp(2*sim) == exp2(acc) with no extra multiplies in the epilogue.
#define PRESCALE 1.69864362f

__device__ __forceinline__ unsigned short f2bf(float f) {
    unsigned int u = __builtin_bit_cast(unsigned int, f);
    u = (u + 0x7fffu + ((u >> 16) & 1u)) >> 16;   // round-to-nearest-even
    return (unsigned short)u;
}

__device__ __forceinline__ void async_copy16(const void* g, void* l) {
    __builtin_amdgcn_global_load_lds((const __attribute__((address_space(1))) void*)g,
                                     (__attribute__((address_space(3))) void*)l,
                                     16, 0, 0);
}

// ---------------------------------------------------------------------------
// Kernel 1: L2-normalize rows of zi/zj -> bf16 zb[8192][256] (scaled by
// PRESCALE); fused positive-pair dots in fp32 (unscaled).
// ---------------------------------------------------------------------------
__global__ __launch_bounds__(256) void norm_kernel(const float* __restrict__ zi,
                                                   const float* __restrict__ zj,
                                                   unsigned short* __restrict__ zb,
                                                   float* __restrict__ posPart) {
    __shared__ float buf[2][256];
    const int wid  = threadIdx.x >> 6;
    const int lane = threadIdx.x & 63;
    const int pair = blockIdx.x * 2 + (wid & 1);    // 0..4095
    const bool isZj = (wid >= 2);
    const float* src = isZj ? (zj + (size_t)pair * DIM) : (zi + (size_t)pair * DIM);
    float4 v = ((const float4*)src)[lane];
    float ss = v.x * v.x + v.y * v.y + v.z * v.z + v.w * v.w;
    #pragma unroll
    for (int off = 1; off < 64; off <<= 1) ss += __shfl_xor(ss, off);
    float inv = 1.0f / fmaxf(sqrtf(ss), 1e-12f);
    float4 nv = make_float4(v.x * inv, v.y * inv, v.z * inv, v.w * inv);

    const int outRow = isZj ? (pair + BSZ) : pair;
    ushort4 o;
    o.x = f2bf(nv.x * PRESCALE); o.y = f2bf(nv.y * PRESCALE);
    o.z = f2bf(nv.z * PRESCALE); o.w = f2bf(nv.w * PRESCALE);
    ((ushort4*)(zb + (size_t)outRow * DIM))[lane] = o;

    if (!isZj) ((float4*)&buf[wid & 1][0])[lane] = nv;
    __syncthreads();
    if (isZj) {
        float4 a = ((float4*)&buf[wid & 1][0])[lane];
        float d = a.x * nv.x + a.y * nv.y + a.z * nv.z + a.w * nv.w;
        #pragma unroll
        for (int off = 1; off < 64; off <<= 1) d += __shfl_xor(d, off);
        if (lane == 0) posPart[pair] = d;
    }
}

// ---------------------------------------------------------------------------
// Kernel 2: symmetric fused Z*Z^T -> exp2 -> partial row AND col sums.
// 256x256 tile, BK=32, 8 waves (2x4), 512 threads, 528 upper-tri blocks.
// Phase-split schedule: per K-tile 2 phases x 16 MFMA, setprio around MFMA,
// stages of tile kt+1 issued in phase A, counted vmcnt, raw barriers.
// LDS 64 KB static: 2 dbuf x (A 16KB + B 16KB), round-4 pair-swizzle
// (conflict-free, involution applied on global source + LDS read).
// Slots: row-sums -> bj*4+wc; col-sums -> bi*4 + wr*2 + msplit.
// ---------------------------------------------------------------------------
__global__ __launch_bounds__(512, 2) void sim_kernel(const unsigned short* __restrict__ zb,
                                                     float* __restrict__ partial) {
    __shared__ alignas(16) char smem[65536];   // tiles; reused as epilogue scratch

    const int t    = threadIdx.x;   // 0..511
    const int lane = t & 63;
    const int wid  = t >> 6;        // 0..7
    const int wr   = wid >> 2;      // 0..1
    const int wc   = wid & 3;       // 0..3
    const int g    = lane >> 4;     // 0..3
    const int c15  = lane & 15;

    // XCD-aware bijective swizzle (528 = 8 * 66), then upper-tri decode
    const int orig = blockIdx.x;
    const int swz  = (orig & 7) * 66 + (orig >> 3);
    int bi = (int)((65.0f - sqrtf(4225.0f - 8.0f * (float)swz)) * 0.5f);
    while (bi * 32 - bi * (bi - 1) / 2 > swz) bi--;
    while ((bi + 1) * 32 - (bi + 1) * bi / 2 <= swz) bi++;
    const int bj = bi + (swz - (bi * 32 - bi * (bi - 1) / 2));
    const bool diag = (bi == bj);

    const int row0 = bi * 256;
    const int col0 = bj * 256;

    f32x4 acc[8][4];
    #pragma unroll
    for (int m = 0; m < 8; m++)
        #pragma unroll
        for (int n = 0; n < 4; n++) acc[m][n] = (f32x4){0.f, 0.f, 0.f, 0.f};

    // Stage one BK=32 K-tile (A 256x32 + B 256x32) into buffer b.
    // 4 gload_lds per thread. Linear LDS dest; source applies the involution:
    // chunk e in [0,1024): pr=e>>3, c=(e&7)^(pr&7), row=pr*2+(c>>2), q=c&3.
    #define STAGE(b, kt) do {                                                   \
        _Pragma("unroll")                                                       \
        for (int i = 0; i < 2; i++) {                                           \
            const int e_  = i * 512 + t;                                        \
            const int pr_ = e_ >> 3;                                            \
            const int c_  = (e_ & 7) ^ (pr_ & 7);                               \
            const int r_  = pr_ * 2 + (c_ >> 2);                                \
            const int q_  = c_ & 3;                                             \
            char* ldsbase = smem + (b) * 32768 + (i * 512 + wid * 64) * 16;     \
            async_copy16(zb + (size_t)(row0 + r_) * DIM + (kt) * 32 + q_ * 8,   \
                         ldsbase);                                              \
            async_copy16(zb + (size_t)(col0 + r_) * DIM + (kt) * 32 + q_ * 8,   \
                         ldsbase + 16384);                                      \
        } } while (0)

    STAGE(0, 0);
    STAGE(1, 1);
    asm volatile("s_waitcnt vmcnt(4)" ::: "memory");   // tile 0 landed; tile 1 in flight
    __builtin_amdgcn_s_barrier();

    #pragma unroll
    for (int kt = 0; kt < 8; ++kt) {
        const int cur = kt & 1;
        const char* Ab = smem + cur * 32768;
        const char* Bb = Ab + 16384;
        const int q = g;                 // 16B k-chunk index (BK=32 -> 4 chunks)

        // ---------- phase A: stage kt+1; read B-frags + A-frags m0..3; 16 MFMA
        if (kt < 7) STAGE(cur ^ 1, kt + 1);
        bf16x8 bfr[4], af[4];
        #pragma unroll
        for (int n = 0; n < 4; n++) {
            const int rr  = wc * 64 + n * 16 + c15;
            const int pr_ = rr >> 1;
            const int sl_ = (((rr & 1) << 2) | q) ^ (pr_ & 7);
            bfr[n] = *(const bf16x8*)(Bb + pr_ * 128 + sl_ * 16);
        }
        #pragma unroll
        for (int m = 0; m < 4; m++) {
            const int rr  = wr * 128 + m * 16 + c15;
            const int pr_ = rr >> 1;
            const int sl_ = (((rr & 1) << 2) | q) ^ (pr_ & 7);
            af[m] = *(const bf16x8*)(Ab + pr_ * 128 + sl_ * 16);
        }
        __builtin_amdgcn_sched_barrier(0);
        __builtin_amdgcn_s_setprio(1);
        #pragma unroll
        for (int m = 0; m < 4; m++)
            #pragma unroll
            for (int n = 0; n < 4; n++)
                acc[m][n] = __builtin_amdgcn_mfma_f32_16x16x32_bf16(af[m], bfr[n], acc[m][n], 0, 0, 0);
        __builtin_amdgcn_s_setprio(0);
        __builtin_amdgcn_sched_barrier(0);
        __builtin_amdgcn_s_barrier();

        // ---------- phase B: read A-frags m4..7; 16 MFMA; boundary wait
        #pragma unroll
        for (int m = 0; m < 4; m++) {
            const int rr  = wr * 128 + (m + 4) * 16 + c15;
            const int pr_ = rr >> 1;
            const int sl_ = (((rr & 1) << 2) | q) ^ (pr_ & 7);
            af[m] = *(const bf16x8*)(Ab + pr_ * 128 + sl_ * 16);
        }
        __builtin_amdgcn_sched_barrier(0);
        __builtin_amdgcn_s_setprio(1);
        #pragma unroll
        for (int m = 0; m < 4; m++)
            #pragma unroll
            for (int n = 0; n < 4; n++)
                acc[m + 4][n] = __builtin_amdgcn_mfma_f32_16x16x32_bf16(af[m], bfr[n], acc[m + 4][n], 0, 0, 0);
        __builtin_amdgcn_s_setprio(0);
        __builtin_amdgcn_sched_barrier(0);
        if (kt < 7) asm volatile("s_waitcnt vmcnt(0)" ::: "memory");  // kt+1 landed
        __builtin_amdgcn_s_barrier();
    }
    #undef STAGE

    // ---- epilogue: exp2(acc); row sums + col sums (off-diag) ----
    float rsumN[8][4];             // per (m, j): sum over this lane's 4 n-frags
    float csum[4][2];              // per (n, m-half): sum over j (this lane's rows)
    #pragma unroll
    for (int m = 0; m < 8; m++)
        #pragma unroll
        for (int j = 0; j < 4; j++) rsumN[m][j] = 0.f;
    #pragma unroll
    for (int n = 0; n < 4; n++) { csum[n][0] = 0.f; csum[n][1] = 0.f; }

    const int colbase = col0 + wc * 64 + c15;
    const int rowbase = row0 + wr * 128 + (g << 2);
    #pragma unroll
    for (int m = 0; m < 8; m++) {
        #pragma unroll
        for (int n = 0; n < 4; n++) {
            const int colg = colbase + n * 16;
            #pragma unroll
            for (int j = 0; j < 4; j++) {
                const int rowg = rowbase + m * 16 + j;
                float e = exp2f(acc[m][n][j]);
                if (diag && rowg == colg) e = 0.0f;
                rsumN[m][j] += e;
                csum[n][m >> 2] += e;
            }
        }
    }

    // col sums: reduce over the 4 row-groups (lane>>4); 16-lane stores.
    if (!diag) {
        #pragma unroll
        for (int n = 0; n < 4; n++)
            #pragma unroll
            for (int ms = 0; ms < 2; ms++) {
                float s = csum[n][ms];
                s += __shfl_xor(s, 16);
                s += __shfl_xor(s, 32);
                csum[n][ms] = s;
            }
        if (lane < 16) {
            #pragma unroll
            for (int ms = 0; ms < 2; ms++) {
                float* dst = partial + (size_t)(bi * 4 + wr * 2 + ms) * N_TOT;
                #pragma unroll
                for (int n = 0; n < 4; n++)
                    dst[colbase + n * 16] = csum[n][ms];
            }
        }
    }

    // row sums: wave-private LDS transpose [64][20] f32, two m-half passes,
    // each ending in a fully-coalesced 64-lane store. Tile LDS is dead here
    // (final phase ended with s_barrier; all waves' ds_reads complete).
    float* sw = (float*)smem + wid * 1280;    // 5120 B per wave, 40 KB total
    #pragma unroll
    for (int ms = 0; ms < 2; ms++) {
        if (ms) {  // WAR: pass-0 reads must finish before pass-1 writes
            asm volatile("s_waitcnt lgkmcnt(0)" ::: "memory");
            __builtin_amdgcn_sched_barrier(0);
        }
        #pragma unroll
        for (int mq = 0; mq < 4; mq++)
            #pragma unroll
            for (int j = 0; j < 4; j++)
                sw[(mq * 16 + (g << 2) + j) * 20 + c15] = rsumN[ms * 4 + mq][j];
        asm volatile("s_waitcnt lgkmcnt(0)" ::: "memory");
        __builtin_amdgcn_sched_barrier(0);
        f32x4 v0 = *(const f32x4*)(sw + lane * 20 + 0);
        f32x4 v1 = *(const f32x4*)(sw + lane * 20 + 4);
        f32x4 v2 = *(const f32x4*)(sw + lane * 20 + 8);
        f32x4 v3 = *(const f32x4*)(sw + lane * 20 + 12);
        float tot = (v0[0] + v0[1] + v0[2] + v0[3]) + (v1[0] + v1[1] + v1[2] + v1[3])
                  + (v2[0] + v2[1] + v2[2] + v2[3]) + (v3[0] + v3[1] + v3[2] + v3[3]);
        partial[(size_t)(bj * 4 + wc) * N_TOT + row0 + wr * 128 + ms * 64 + lane] = tot;
    }
}

// ---------------------------------------------------------------------------
// Kernel 3: per-row sum of 128 partials -> log(negsum+eps). Grid 128 blocks,
// each block = 64 rows; wave w sums slots [w*32, w*32+32).
// ---------------------------------------------------------------------------
__global__ __launch_bounds__(256) void rowlog_kernel(const float* __restrict__ partial,
                                                     float* __restrict__ logPart) {
    const int lane = threadIdx.x & 63;
    const int w    = threadIdx.x >> 6;
    const int row  = blockIdx.x * 64 + lane;
    float s = 0.f;
    #pragma unroll 8
    for (int p = w * 32; p < w * 32 + 32; p++) s += partial[(size_t)p * N_TOT + row];
    __shared__ float red[4][64];
    red[w][lane] = s;
    __syncthreads();
    if (w == 0) {
        float tot = red[0][lane] + red[1][lane] + red[2][lane] + red[3][lane];
        float v = logf(tot + 1e-8f);
        #pragma unroll
        for (int off = 1; off < 64; off <<= 1) v += __shfl_xor(v, off);
        if (lane == 0) logPart[blockIdx.x] = v;
    }
}

// ---------------------------------------------------------------------------
// Kernel 4: final scalar: loss = mean(log terms) - 2*sum(dots)/BSZ
// ---------------------------------------------------------------------------
__global__ __launch_bounds__(256) void final_kernel(const float* __restrict__ logPart,
                                                    const float* __restrict__ posPart,
                                                    float* __restrict__ out) {
    const int t = threadIdx.x;
    float ps = 0.f;
    for (int i = t; i < BSZ; i += 256) ps += posPart[i];
    float ls = (t < 128) ? logPart[t] : 0.f;
    #pragma unroll
    for (int off = 1; off < 64; off <<= 1) {
        ps += __shfl_xor(ps, off);
        ls += __shfl_xor(ls, off);
    }
    __shared__ float redp[4], redl[4];
    const int lane = t & 63, wid = t >> 6;
    if (lane == 0) { redp[wid] = ps; redl[wid] = ls; }
    __syncthreads();
    if (t == 0) {
        const float posSum = redp[0] + redp[1] + redp[2] + redp[3];
        const float logSum = redl[0] + redl[1] + redl[2] + redl[3];
        out[0] = logSum / (float)N_TOT - 2.0f * posSum / (float)BSZ;
    }
}

extern "C" void kernel_launch(void* const* d_in, const int* in_sizes, int n_in,
                              void* d_out, int out_size, void* d_ws, size_t ws_size,
                              hipStream_t stream) {
    const float* zi = (const float*)d_in[0];
    const float* zj = (const float*)d_in[1];
    float* out = (float*)d_out;

    char* ws = (char*)d_ws;
    unsigned short* zb = (unsigned short*)ws;                    // 8192*256*2 = 4 MB
    float* partial     = (float*)(ws + (size_t)(4 << 20));       // 128*8192*4 = 4 MB
    float* logPart     = (float*)(ws + (size_t)(8 << 20));       // 128 floats
    float* posPart     = (float*)(ws + (size_t)(8 << 20) + 4096);// 4096 floats

    norm_kernel<<<2048, 256, 0, stream>>>(zi, zj, zb, posPart);
    sim_kernel<<<528, 512, 0, stream>>>(zb, partial);
    rowlog_kernel<<<128, 256, 0, stream>>>(partial, logPart);
    final_kernel<<<1, 256, 0, stream>>>(logPart, posPart, out);
}

// Round 6
// 49.701 us; speedup vs baseline: 1.0722x; 1.0722x over previous
//
#include <hip/hip_runtime.h>

#define N_TOT 8192
#define BSZ   4096
#define DIM   256

typedef __attribute__((ext_vector_type(8))) short bf16x8;
typedef __attribute__((ext_vector_type(4))) float f32x4;

// zb is pre-scaled by sqrt(2*log2(e)) so that acc = 2*log2(e)*sim and
// exp(2*sim) == exp2(acc) with no extra multiplies in the epilogue.
#define PRESCALE 1.69864362f

__device__ __forceinline__ unsigned short f2bf(float f) {
    unsigned int u = __builtin_bit_cast(unsigned int, f);
    u = (u + 0x7fffu + ((u >> 16) & 1u)) >> 16;   // round-to-nearest-even
    return (unsigned short)u;
}

__device__ __forceinline__ void async_copy16(const void* g, void* l) {
    __builtin_amdgcn_global_load_lds((const __attribute__((address_space(1))) void*)g,
                                     (__attribute__((address_space(3))) void*)l,
                                     16, 0, 0);
}

// ---------------------------------------------------------------------------
// Kernel 1: L2-normalize rows of zi/zj -> bf16 zb[8192][256] (scaled by
// PRESCALE); fused positive-pair dots in fp32 (unscaled).
// ---------------------------------------------------------------------------
__global__ __launch_bounds__(256) void norm_kernel(const float* __restrict__ zi,
                                                   const float* __restrict__ zj,
                                                   unsigned short* __restrict__ zb,
                                                   float* __restrict__ posPart) {
    __shared__ float buf[2][256];
    const int wid  = threadIdx.x >> 6;
    const int lane = threadIdx.x & 63;
    const int pair = blockIdx.x * 2 + (wid & 1);    // 0..4095
    const bool isZj = (wid >= 2);
    const float* src = isZj ? (zj + (size_t)pair * DIM) : (zi + (size_t)pair * DIM);
    float4 v = ((const float4*)src)[lane];
    float ss = v.x * v.x + v.y * v.y + v.z * v.z + v.w * v.w;
    #pragma unroll
    for (int off = 1; off < 64; off <<= 1) ss += __shfl_xor(ss, off);
    float inv = 1.0f / fmaxf(sqrtf(ss), 1e-12f);
    float4 nv = make_float4(v.x * inv, v.y * inv, v.z * inv, v.w * inv);

    const int outRow = isZj ? (pair + BSZ) : pair;
    ushort4 o;
    o.x = f2bf(nv.x * PRESCALE); o.y = f2bf(nv.y * PRESCALE);
    o.z = f2bf(nv.z * PRESCALE); o.w = f2bf(nv.w * PRESCALE);
    ((ushort4*)(zb + (size_t)outRow * DIM))[lane] = o;

    if (!isZj) ((float4*)&buf[wid & 1][0])[lane] = nv;
    __syncthreads();
    if (isZj) {
        float4 a = ((float4*)&buf[wid & 1][0])[lane];
        float d = a.x * nv.x + a.y * nv.y + a.z * nv.z + a.w * nv.w;
        #pragma unroll
        for (int off = 1; off < 64; off <<= 1) d += __shfl_xor(d, off);
        if (lane == 0) posPart[pair] = d;
    }
}

// ---------------------------------------------------------------------------
// Kernel 2: symmetric fused Z*Z^T -> exp2 -> partial row AND col sums.
// Pair-jobs: each block handles tiles (bi,bj1) and (bi,bj1+1) of the upper
// triangle, SHARING the A-fragments in registers (32 MFMA per 12 ds_reads).
// 1056 uniform-cost jobs (odd leftovers duplicate tile 1, skip stores).
// 128x128 tiles, BK=32, 8 K-phases, 4 waves (2x2), 64x(64+64) per wave.
// LDS 48 KB = 2 dbuf x (A 8K + B1 8K + B2 8K), round-4 pair-swizzle
// (conflict-free, involution on global source + LDS read).
// Schedule: ONE barrier per phase; stage of kt+1 issued after the barrier
// (WAR-safe: previous readers of that buffer finished pre-barrier); vmcnt
// drains loads that are a full phase old (~free); setprio on MFMA cluster.
// Slots: row-sums -> bj*2+wc; col-sums -> bi*2+wr.
// ---------------------------------------------------------------------------
__global__ __launch_bounds__(256, 2) void sim_kernel(const unsigned short* __restrict__ zb,
                                                     float* __restrict__ partial) {
    __shared__ alignas(16) char smem[49152];   // tiles; reused as epilogue scratch

    const int t    = threadIdx.x;
    const int lane = t & 63;
    const int wid  = t >> 6;
    const int wr   = wid >> 1;     // 0..1
    const int wc   = wid & 1;      // 0..1
    const int g    = lane >> 4;    // 0..3
    const int c15  = lane & 15;

    // ---- job decode: k -> (bi, t) with J(bi)=32-(bi>>1) jobs per row ----
    auto S = [](int b) { int mm = b >> 1; return mm * (65 - mm) + ((b & 1) ? (32 - mm) : 0); };
    const int k = blockIdx.x;                       // 0..1055
    int bi = 2 * (int)((65.0f - sqrtf(fmaxf(4225.0f - 4.0f * (float)k, 0.f))) * 0.5f);
    if (bi < 0) bi = 0; if (bi > 63) bi = 63;
    while (bi > 0 && S(bi) > k) bi--;
    while (S(bi + 1) <= k) bi++;
    const int tt   = k - S(bi);
    const int bj1  = bi + 2 * tt;
    const bool valid2 = (bj1 + 1) <= 63;
    const bool diag   = (bi == bj1);
    const int row0 = bi * 128;
    const int col1 = bj1 * 128;
    const int col2 = valid2 ? col1 + 128 : col1;    // duplicate if single

    f32x4 acc[2][4][4];
    #pragma unroll
    for (int jj = 0; jj < 2; jj++)
        #pragma unroll
        for (int m = 0; m < 4; m++)
            #pragma unroll
            for (int n = 0; n < 4; n++) acc[jj][m][n] = (f32x4){0.f, 0.f, 0.f, 0.f};

    // Stage one BK=32 K-slice of A, B1, B2 into buffer b (6 gload_lds/thread).
    // Linear LDS dest; source applies the involution (pair-swizzle).
    #define STAGE(b, kt) do {                                                   \
        _Pragma("unroll")                                                       \
        for (int i = 0; i < 2; i++) {                                           \
            const int e_  = i * 256 + t;       /* 16B chunk 0..511 */           \
            const int pr_ = e_ >> 3;           /* LDS pair-row */               \
            const int c_  = (e_ & 7) ^ (pr_ & 7);                               \
            const int r_  = pr_ * 2 + (c_ >> 2);                                \
            const int q_  = c_ & 3;                                             \
            char* lb = smem + (b) * 24576 + (i * 256 + wid * 64) * 16;          \
            const size_t ko = (size_t)(kt) * 32 + q_ * 8;                       \
            async_copy16(zb + (size_t)(row0 + r_) * DIM + ko, lb);              \
            async_copy16(zb + (size_t)(col1 + r_) * DIM + ko, lb + 8192);       \
            async_copy16(zb + (size_t)(col2 + r_) * DIM + ko, lb + 16384);      \
        } } while (0)

    STAGE(0, 0);   // prologue

    #pragma unroll
    for (int kt = 0; kt < 8; ++kt) {
        // kt's loads are one full phase old here -> near-free drain
        asm volatile("s_waitcnt vmcnt(0)" ::: "memory");
        __builtin_amdgcn_sched_barrier(0);
        __builtin_amdgcn_s_barrier();
        if (kt < 7) STAGE((kt + 1) & 1, kt + 1);   // WAR-safe post-barrier

        const char* Ab = smem + (kt & 1) * 24576;
        bf16x8 af[4], b1[4], b2[4];
        #pragma unroll
        for (int m = 0; m < 4; m++) {
            const int rr = wr * 64 + m * 16 + c15;
            const int pr = rr >> 1;
            const int sl = (((rr & 1) << 2) | g) ^ (pr & 7);
            af[m] = *(const bf16x8*)(Ab + pr * 128 + sl * 16);
        }
        #pragma unroll
        for (int n = 0; n < 4; n++) {
            const int rr = wc * 64 + n * 16 + c15;
            const int pr = rr >> 1;
            const int sl = (((rr & 1) << 2) | g) ^ (pr & 7);
            b1[n] = *(const bf16x8*)(Ab + 8192  + pr * 128 + sl * 16);
            b2[n] = *(const bf16x8*)(Ab + 16384 + pr * 128 + sl * 16);
        }
        __builtin_amdgcn_s_setprio(1);
        #pragma unroll
        for (int m = 0; m < 4; m++)
            #pragma unroll
            for (int n = 0; n < 4; n++) {
                acc[0][m][n] = __builtin_amdgcn_mfma_f32_16x16x32_bf16(af[m], b1[n], acc[0][m][n], 0, 0, 0);
                acc[1][m][n] = __builtin_amdgcn_mfma_f32_16x16x32_bf16(af[m], b2[n], acc[1][m][n], 0, 0, 0);
            }
        __builtin_amdgcn_s_setprio(0);
        __builtin_amdgcn_sched_barrier(0);
    }
    #undef STAGE
    __builtin_amdgcn_s_barrier();   // all tile reads done; smem reusable

    // ---- epilogue: exp2; per-tile row sums + col sums ----
    const int rowbase = row0 + wr * 64 + (g << 2);
    float* sw = (float*)smem + wid * 1280;        // per-wave [64][20] f32

    #pragma unroll
    for (int jj = 0; jj < 2; jj++) {
        const bool active = (jj == 0) || valid2;
        const bool dg     = (jj == 0) && diag;
        const int col0j   = jj ? col2 : col1;
        const int colbase = col0j + wc * 64 + c15;

        float rsum[4][4];
        float csum[4];
        #pragma unroll
        for (int m = 0; m < 4; m++)
            #pragma unroll
            for (int j = 0; j < 4; j++) rsum[m][j] = 0.f;
        #pragma unroll
        for (int n = 0; n < 4; n++) csum[n] = 0.f;

        #pragma unroll
        for (int m = 0; m < 4; m++) {
            #pragma unroll
            for (int n = 0; n < 4; n++) {
                const int colg = colbase + n * 16;
                #pragma unroll
                for (int j = 0; j < 4; j++) {
                    const int rowg = rowbase + m * 16 + j;
                    float e = exp2f(acc[jj][m][n][j]);
                    if (dg && rowg == colg) e = 0.0f;
                    rsum[m][j] += e;
                    csum[n] += e;
                }
            }
        }

        // col sums -> slot bi*2+wr (rows = cols of this bj block); skip diag
        if (!dg) {
            #pragma unroll
            for (int n = 0; n < 4; n++) {
                float s = csum[n];
                s += __shfl_xor(s, 16);
                s += __shfl_xor(s, 32);
                csum[n] = s;
            }
            if (active && lane < 16) {
                float* dst = partial + (size_t)(bi * 2 + wr) * N_TOT;
                #pragma unroll
                for (int n = 0; n < 4; n++)
                    dst[colbase + n * 16] = csum[n];
            }
        }

        // row sums via wave-private LDS transpose -> coalesced 64-lane store
        if (jj) {   // WAR vs jj=0 reads of the same scratch
            asm volatile("s_waitcnt lgkmcnt(0)" ::: "memory");
            __builtin_amdgcn_sched_barrier(0);
        }
        #pragma unroll
        for (int m = 0; m < 4; m++)
            #pragma unroll
            for (int j = 0; j < 4; j++)
                sw[(m * 16 + (g << 2) + j) * 20 + c15] = rsum[m][j];
        asm volatile("s_waitcnt lgkmcnt(0)" ::: "memory");
        __builtin_amdgcn_sched_barrier(0);
        f32x4 v0 = *(const f32x4*)(sw + lane * 20 + 0);
        f32x4 v1 = *(const f32x4*)(sw + lane * 20 + 4);
        f32x4 v2 = *(const f32x4*)(sw + lane * 20 + 8);
        f32x4 v3 = *(const f32x4*)(sw + lane * 20 + 12);
        float tot = (v0[0] + v0[1] + v0[2] + v0[3]) + (v1[0] + v1[1] + v1[2] + v1[3])
                  + (v2[0] + v2[1] + v2[2] + v2[3]) + (v3[0] + v3[1] + v3[2] + v3[3]);
        if (active) {
            const int bj = bj1 + jj;
            partial[(size_t)(bj * 2 + wc) * N_TOT + row0 + wr * 64 + lane] = tot;
        }
    }
}

// ---------------------------------------------------------------------------
// Kernel 3: per-row sum of 128 partials -> log(negsum+eps). Grid 128 blocks,
// each block = 64 rows; wave w sums slots [w*32, w*32+32).
// ---------------------------------------------------------------------------
__global__ __launch_bounds__(256) void rowlog_kernel(const float* __restrict__ partial,
                                                     float* __restrict__ logPart) {
    const int lane = threadIdx.x & 63;
    const int w    = threadIdx.x >> 6;
    const int row  = blockIdx.x * 64 + lane;
    float s = 0.f;
    #pragma unroll 8
    for (int p = w * 32; p < w * 32 + 32; p++) s += partial[(size_t)p * N_TOT + row];
    __shared__ float red[4][64];
    red[w][lane] = s;
    __syncthreads();
    if (w == 0) {
        float tot = red[0][lane] + red[1][lane] + red[2][lane] + red[3][lane];
        float v = logf(tot + 1e-8f);
        #pragma unroll
        for (int off = 1; off < 64; off <<= 1) v += __shfl_xor(v, off);
        if (lane == 0) logPart[blockIdx.x] = v;
    }
}

// ---------------------------------------------------------------------------
// Kernel 4: final scalar: loss = mean(log terms) - 2*sum(dots)/BSZ
// ---------------------------------------------------------------------------
__global__ __launch_bounds__(256) void final_kernel(const float* __restrict__ logPart,
                                                    const float* __restrict__ posPart,
                                                    float* __restrict__ out) {
    const int t = threadIdx.x;
    float ps = 0.f;
    for (int i = t; i < BSZ; i += 256) ps += posPart[i];
    float ls = (t < 128) ? logPart[t] : 0.f;
    #pragma unroll
    for (int off = 1; off < 64; off <<= 1) {
        ps += __shfl_xor(ps, off);
        ls += __shfl_xor(ls, off);
    }
    __shared__ float redp[4], redl[4];
    const int lane = t & 63, wid = t >> 6;
    if (lane == 0) { redp[wid] = ps; redl[wid] = ls; }
    __syncthreads();
    if (t == 0) {
        const float posSum = redp[0] + redp[1] + redp[2] + redp[3];
        const float logSum = redl[0] + redl[1] + redl[2] + redl[3];
        out[0] = logSum / (float)N_TOT - 2.0f * posSum / (float)BSZ;
    }
}

extern "C" void kernel_launch(void* const* d_in, const int* in_sizes, int n_in,
                              void* d_out, int out_size, void* d_ws, size_t ws_size,
                              hipStream_t stream) {
    const float* zi = (const float*)d_in[0];
    const float* zj = (const float*)d_in[1];
    float* out = (float*)d_out;

    char* ws = (char*)d_ws;
    unsigned short* zb = (unsigned short*)ws;                    // 8192*256*2 = 4 MB
    float* partial     = (float*)(ws + (size_t)(4 << 20));       // 128*8192*4 = 4 MB
    float* logPart     = (float*)(ws + (size_t)(8 << 20));       // 128 floats
    float* posPart     = (float*)(ws + (size_t)(8 << 20) + 4096);// 4096 floats

    norm_kernel<<<2048, 256, 0, stream>>>(zi, zj, zb, posPart);
    sim_kernel<<<1056, 256, 0, stream>>>(zb, partial);
    rowlog_kernel<<<128, 256, 0, stream>>>(partial, logPart);
    final_kernel<<<1, 256, 0, stream>>>(logPart, posPart, out);
}

// Round 7
// 38.570 us; speedup vs baseline: 1.3816x; 1.2886x over previous
//
#include <hip/hip_runtime.h>

#define N_TOT 8192
#define BSZ   4096
#define DIM   256

typedef __attribute__((ext_vector_type(4))) float f32x4;
typedef __attribute__((ext_vector_type(2))) unsigned long long u64x2;

// zb is pre-scaled by sqrt(2*log2(e)) so that acc = 2*log2(e)*sim and
// exp(2*sim) == exp2(acc) with no extra multiplies in the epilogue.
#define PRESCALE 1.69864362f

__device__ __forceinline__ void async_copy16(const void* g, void* l) {
    __builtin_amdgcn_global_load_lds((const __attribute__((address_space(1))) void*)g,
                                     (__attribute__((address_space(3))) void*)l,
                                     16, 0, 0);
}

// ---------------------------------------------------------------------------
// Kernel 1: L2-normalize rows of zi/zj -> fp8 e4m3 zb[8192][256B] (scaled by
// PRESCALE) in PERMUTED row layout; fused positive-pair dots in fp32.
//
// Row layout: 8-block j (elements k=8j..8j+8) lives at byte offset
//   F(j) = (j>>3)*64 + (j&3)*16 + ((j>>2)&1)*8
// so each 16B chunk c = kt*4+g holds {k=kt*64+g*8..+8} ++ {k=kt*64+32+g*8..+8}
// i.e. one ds_read_b128 = both K-half MFMA operands for a lane.
// ---------------------------------------------------------------------------
__global__ __launch_bounds__(256) void norm_kernel(const float* __restrict__ zi,
                                                   const float* __restrict__ zj,
                                                   unsigned char* __restrict__ zb,
                                                   float* __restrict__ posPart) {
    __shared__ float buf[2][256];
    const int wid  = threadIdx.x >> 6;
    const int lane = threadIdx.x & 63;
    const int pair = blockIdx.x * 2 + (wid & 1);    // 0..4095
    const bool isZj = (wid >= 2);
    const float* src = isZj ? (zj + (size_t)pair * DIM) : (zi + (size_t)pair * DIM);
    float4 v = ((const float4*)src)[lane];
    float ss = v.x * v.x + v.y * v.y + v.z * v.z + v.w * v.w;
    #pragma unroll
    for (int off = 1; off < 64; off <<= 1) ss += __shfl_xor(ss, off);
    float inv = 1.0f / fmaxf(sqrtf(ss), 1e-12f);
    float4 nv = make_float4(v.x * inv, v.y * inv, v.z * inv, v.w * inv);

    const int outRow = isZj ? (pair + BSZ) : pair;
    // lane holds elements k = 4*lane .. 4*lane+3  ->  8-block j8 = lane>>1,
    // byte = F(j8) + (lane&1)*4. Pack 4 fp8 (OCP e4m3 on gfx950) into an int.
    const int j8  = lane >> 1;
    const int off4 = ((j8 >> 3) << 6) + ((j8 & 3) << 4) + (((j8 >> 2) & 1) << 3)
                   + ((lane & 1) << 2);
    int pk = __builtin_amdgcn_cvt_pk_fp8_f32(nv.x * PRESCALE, nv.y * PRESCALE, 0, false);
    pk     = __builtin_amdgcn_cvt_pk_fp8_f32(nv.z * PRESCALE, nv.w * PRESCALE, pk, true);
    *(int*)(zb + (size_t)outRow * 256 + off4) = pk;

    if (!isZj) ((float4*)&buf[wid & 1][0])[lane] = nv;
    __syncthreads();
    if (isZj) {
        float4 a = ((float4*)&buf[wid & 1][0])[lane];
        float d = a.x * nv.x + a.y * nv.y + a.z * nv.z + a.w * nv.w;
        #pragma unroll
        for (int off = 1; off < 64; off <<= 1) d += __shfl_xor(d, off);
        if (lane == 0) posPart[pair] = d;
    }
}

// ---------------------------------------------------------------------------
// Kernel 2: symmetric fused Z*Z^T -> exp2 -> partial row AND col sums.
// fp8 e4m3 operands, mfma_f32_16x16x32_fp8_fp8, upper-tri 2080 blocks,
// 128x128 tile, BK=64 per phase (4 phases), double-buffered 32 KB LDS,
// counted vmcnt(4) (round-4 schedule), 16 waves/CU.
//
// LDS tile: [128 rows][4 phys chunks of 16B]; phys p = g ^ ((rr>>1)&3)
// (involution; 2 lanes/slot per quarter-wave -> conflict-free).
// One ds_read_b128 per frag = operands for kk=0 (lo 8B) and kk=1 (hi 8B).
// Slots: row-sums -> bj*2+wc; col-sums -> bi*2+wr.
// ---------------------------------------------------------------------------
__global__ __launch_bounds__(256, 4) void sim_kernel(const unsigned char* __restrict__ zb,
                                                     float* __restrict__ partial) {
    __shared__ alignas(16) char smem[32768];   // 2 dbuf x (A 8K + B 8K); epi scratch

    const int t    = threadIdx.x;
    const int lane = t & 63;
    const int wid  = t >> 6;
    const int wr   = wid >> 1;     // 0..1
    const int wc   = wid & 1;      // 0..1
    const int g    = lane >> 4;    // 0..3  (logical 16B chunk / K-group)
    const int c15  = lane & 15;

    // decode upper-triangular (bi, bj), bi <= bj, from linear block id
    const int k = blockIdx.x;                       // 0..2079
    int bi = (int)((129.0f - sqrtf(16641.0f - 8.0f * (float)k)) * 0.5f);
    while (bi * 64 - bi * (bi - 1) / 2 > k) bi--;
    while ((bi + 1) * 64 - (bi + 1) * bi / 2 <= k) bi++;
    const int bj = bi + (k - (bi * 64 - bi * (bi - 1) / 2));
    const bool diag = (bi == bj);

    const int row0 = bi * 128;
    const int col0 = bj * 128;

    f32x4 acc[4][4];
    #pragma unroll
    for (int m = 0; m < 4; m++)
        #pragma unroll
        for (int n = 0; n < 4; n++) acc[m][n] = (f32x4){0.f, 0.f, 0.f, 0.f};

    // Stage one BK=64 K-tile (A 128x64B + B 128x64B) into buffer b.
    // 4 gload_lds / thread. Linear LDS dest; source applies the involution.
    #define STAGE(b, kt) do {                                                   \
        _Pragma("unroll")                                                       \
        for (int i = 0; i < 2; i++) {                                           \
            const int e_  = i * 256 + t;       /* 16B slot 0..511 */            \
            const int rr_ = e_ >> 2;           /* tile row 0..127 */            \
            const int p_  = e_ & 3;            /* phys chunk */                 \
            const int g_  = p_ ^ ((rr_ >> 1) & 3);   /* logical chunk */        \
            char* lb = smem + (b) * 16384 + (i * 256 + wid * 64) * 16;          \
            async_copy16(zb + (size_t)(row0 + rr_) * 256 + (kt) * 64 + g_ * 16, \
                         lb);                                                   \
            async_copy16(zb + (size_t)(col0 + rr_) * 256 + (kt) * 64 + g_ * 16, \
                         lb + 8192);                                            \
        } } while (0)

    STAGE(0, 0);   // prologue

    #pragma unroll
    for (int kt = 0; kt < 4; ++kt) {
        const int cur = kt & 1;
        if (kt < 3) {
            STAGE(cur ^ 1, kt + 1);
            asm volatile("s_waitcnt vmcnt(4)" ::: "memory");  // tile kt landed
        } else {
            asm volatile("s_waitcnt vmcnt(0)" ::: "memory");
        }
        __builtin_amdgcn_sched_barrier(0);
        __builtin_amdgcn_s_barrier();

        const char* Ab = smem + cur * 16384;
        const char* Bb = Ab + 8192;
        u64x2 af[4], bfr[4];
        #pragma unroll
        for (int m = 0; m < 4; m++) {
            const int rr = wr * 64 + m * 16 + c15;
            const int p  = g ^ ((rr >> 1) & 3);
            af[m] = *(const u64x2*)(Ab + rr * 64 + p * 16);
        }
        #pragma unroll
        for (int n = 0; n < 4; n++) {
            const int rr = wc * 64 + n * 16 + c15;
            const int p  = g ^ ((rr >> 1) & 3);
            bfr[n] = *(const u64x2*)(Bb + rr * 64 + p * 16);
        }
        #pragma unroll
        for (int m = 0; m < 4; m++)
            #pragma unroll
            for (int n = 0; n < 4; n++) {
                acc[m][n] = __builtin_amdgcn_mfma_f32_16x16x32_fp8_fp8(
                    (long)af[m].x, (long)bfr[n].x, acc[m][n], 0, 0, 0);
                acc[m][n] = __builtin_amdgcn_mfma_f32_16x16x32_fp8_fp8(
                    (long)af[m].y, (long)bfr[n].y, acc[m][n], 0, 0, 0);
            }

        __builtin_amdgcn_sched_barrier(0);
        __builtin_amdgcn_s_barrier();   // buf[cur] free for overwrite next iter
    }
    #undef STAGE

    // ---- epilogue: exp2(acc); row sums (always) + col sums (off-diag) ----
    float rsum[4][4];
    float csum[4];
    #pragma unroll
    for (int m = 0; m < 4; m++)
        #pragma unroll
        for (int j = 0; j < 4; j++) rsum[m][j] = 0.f;
    #pragma unroll
    for (int n = 0; n < 4; n++) csum[n] = 0.f;

    const int colbase = col0 + wc * 64 + c15;
    const int rowbase = row0 + wr * 64 + (g << 2);
    #pragma unroll
    for (int m = 0; m < 4; m++) {
        #pragma unroll
        for (int n = 0; n < 4; n++) {
            const int colg = colbase + n * 16;
            #pragma unroll
            for (int j = 0; j < 4; j++) {
                const int rowg = rowbase + m * 16 + j;
                float e = exp2f(acc[m][n][j]);
                if (diag && rowg == colg) e = 0.0f;
                rsum[m][j] += e;
                csum[n] += e;
            }
        }
    }

    // col sums: reduce over the 4 row-groups; coalesced 16-lane stores
    if (!diag) {
        #pragma unroll
        for (int n = 0; n < 4; n++) {
            float s = csum[n];
            s += __shfl_xor(s, 16);
            s += __shfl_xor(s, 32);
            csum[n] = s;
        }
        if (lane < 16) {
            float* dst = partial + (size_t)(bi * 2 + wr) * N_TOT;
            #pragma unroll
            for (int n = 0; n < 4; n++)
                dst[colbase + n * 16] = csum[n];
        }
    }

    // row sums: wave-private LDS transpose [64][20] f32 -> coalesced store.
    // Safe to reuse smem: loop ended with s_barrier (all tile reads done).
    float* sw = (float*)smem + wid * 1280;        // 5120 B per wave
    #pragma unroll
    for (int m = 0; m < 4; m++)
        #pragma unroll
        for (int j = 0; j < 4; j++)
            sw[(m * 16 + (g << 2) + j) * 20 + c15] = rsum[m][j];
    asm volatile("s_waitcnt lgkmcnt(0)" ::: "memory");
    __builtin_amdgcn_sched_barrier(0);
    f32x4 v0 = *(const f32x4*)(sw + lane * 20 + 0);
    f32x4 v1 = *(const f32x4*)(sw + lane * 20 + 4);
    f32x4 v2 = *(const f32x4*)(sw + lane * 20 + 8);
    f32x4 v3 = *(const f32x4*)(sw + lane * 20 + 12);
    float tot = (v0[0] + v0[1] + v0[2] + v0[3]) + (v1[0] + v1[1] + v1[2] + v1[3])
              + (v2[0] + v2[1] + v2[2] + v2[3]) + (v3[0] + v3[1] + v3[2] + v3[3]);
    partial[(size_t)(bj * 2 + wc) * N_TOT + row0 + wr * 64 + lane] = tot;
}

// ---------------------------------------------------------------------------
// Kernel 3: per-row sum of 128 partials -> log(negsum+eps). Grid 128 blocks,
// each block = 64 rows; wave w sums slots [w*32, w*32+32).
// ---------------------------------------------------------------------------
__global__ __launch_bounds__(256) void rowlog_kernel(const float* __restrict__ partial,
                                                     float* __restrict__ logPart) {
    const int lane = threadIdx.x & 63;
    const int w    = threadIdx.x >> 6;
    const int row  = blockIdx.x * 64 + lane;
    float s = 0.f;
    #pragma unroll 8
    for (int p = w * 32; p < w * 32 + 32; p++) s += partial[(size_t)p * N_TOT + row];
    __shared__ float red[4][64];
    red[w][lane] = s;
    __syncthreads();
    if (w == 0) {
        float tot = red[0][lane] + red[1][lane] + red[2][lane] + red[3][lane];
        float v = logf(tot + 1e-8f);
        #pragma unroll
        for (int off = 1; off < 64; off <<= 1) v += __shfl_xor(v, off);
        if (lane == 0) logPart[blockIdx.x] = v;
    }
}

// ---------------------------------------------------------------------------
// Kernel 4: final scalar: loss = mean(log terms) - 2*sum(dots)/BSZ
// ---------------------------------------------------------------------------
__global__ __launch_bounds__(256) void final_kernel(const float* __restrict__ logPart,
                                                    const float* __restrict__ posPart,
                                                    float* __restrict__ out) {
    const int t = threadIdx.x;
    float ps = 0.f;
    for (int i = t; i < BSZ; i += 256) ps += posPart[i];
    float ls = (t < 128) ? logPart[t] : 0.f;
    #pragma unroll
    for (int off = 1; off < 64; off <<= 1) {
        ps += __shfl_xor(ps, off);
        ls += __shfl_xor(ls, off);
    }
    __shared__ float redp[4], redl[4];
    const int lane = t & 63, wid = t >> 6;
    if (lane == 0) { redp[wid] = ps; redl[wid] = ls; }
    __syncthreads();
    if (t == 0) {
        const float posSum = redp[0] + redp[1] + redp[2] + redp[3];
        const float logSum = redl[0] + redl[1] + redl[2] + redl[3];
        out[0] = logSum / (float)N_TOT - 2.0f * posSum / (float)BSZ;
    }
}

extern "C" void kernel_launch(void* const* d_in, const int* in_sizes, int n_in,
                              void* d_out, int out_size, void* d_ws, size_t ws_size,
                              hipStream_t stream) {
    const float* zi = (const float*)d_in[0];
    const float* zj = (const float*)d_in[1];
    float* out = (float*)d_out;

    char* ws = (char*)d_ws;
    unsigned char* zb = (unsigned char*)ws;                      // 8192*256 = 2 MB
    float* partial     = (float*)(ws + (size_t)(4 << 20));       // 128*8192*4 = 4 MB
    float* logPart     = (float*)(ws + (size_t)(8 << 20));       // 128 floats
    float* posPart     = (float*)(ws + (size_t)(8 << 20) + 4096);// 4096 floats

    norm_kernel<<<2048, 256, 0, stream>>>(zi, zj, zb, posPart);
    sim_kernel<<<2080, 256, 0, stream>>>(zb, partial);
    rowlog_kernel<<<128, 256, 0, stream>>>(partial, logPart);
    final_kernel<<<1, 256, 0, stream>>>(logPart, posPart, out);
}